// Round 1
// baseline (438.028 us; speedup 1.0000x reference)
//
#include <hip/hip_runtime.h>
#include <stdint.h>

// MHA forward: B=4, S=2048, E=1024, H=16, Dh=64, causal, fp32 I/O, bf16 MFMA compute.
//
// Pipeline:
//   1. cvt X -> Xb (bf16 [8192][1024])
//   2. prep_w: Wq/Wk/Wv [16][1024][64] -> Wt bf16 [3072][1024] (B^T layout, K=E contiguous)
//   3. cvt Wo -> Wob bf16 [1024][1024] (already B^T layout for out = A @ Wo^T)
//   4. gemm_bt<0>: QKV[8192][3072] bf16 = Xb @ Wt^T
//   5. mha_attn: flash attention -> AO bf16 [8192][1024]  (AO reuses Xb's ws region)
//   6. gemm_bt<1>: out f32 = AO @ Wob^T + bo

typedef __bf16 bf16_t;
typedef __bf16 bf16x4 __attribute__((ext_vector_type(4)));
typedef __bf16 bf16x8 __attribute__((ext_vector_type(8)));
typedef float  f32x4  __attribute__((ext_vector_type(4)));

union V8 { bf16x8 v8; bf16x4 h[2]; };

#define A_S  2048
#define A_LD 3072

__device__ __forceinline__ void gload_lds16(const void* g, void* l) {
  __builtin_amdgcn_global_load_lds((const __attribute__((address_space(1))) void*)g,
                                   (__attribute__((address_space(3))) void*)l, 16, 0, 0);
}

// ---------------- conversion kernels ----------------

__global__ void mha_cvt_bf16(const float* __restrict__ in, bf16_t* __restrict__ out) {
  size_t i = ((size_t)blockIdx.x * 256 + threadIdx.x) * 8;
  const float4* p = (const float4*)(in + i);
  float4 a = p[0], b = p[1];
  bf16x8 o;
  o[0] = (__bf16)a.x; o[1] = (__bf16)a.y; o[2] = (__bf16)a.z; o[3] = (__bf16)a.w;
  o[4] = (__bf16)b.x; o[5] = (__bf16)b.y; o[6] = (__bf16)b.z; o[7] = (__bf16)b.w;
  *(bf16x8*)(out + i) = o;
}

// Wq/Wk/Wv [H=16][E=1024][Dh=64] fp32 -> Wt [3072][1024] bf16, Wt[mat*1024+h*64+d][e]
__global__ void mha_prep_w(const float* __restrict__ Wq, const float* __restrict__ Wk,
                           const float* __restrict__ Wv, bf16_t* __restrict__ Wt) {
  __shared__ float tile[64][65];
  const int e0 = blockIdx.x * 64;
  const int mh = blockIdx.y;
  const int mat = mh >> 4, h = mh & 15;
  const float* W = (mat == 0) ? Wq : (mat == 1) ? Wk : Wv;
  #pragma unroll
  for (int i = 0; i < 16; i++) {
    int idx = threadIdx.x + i * 256;
    int er = idx >> 6, d = idx & 63;
    tile[er][d] = W[(size_t)(h * 1024 + e0 + er) * 64 + d];
  }
  __syncthreads();
  #pragma unroll
  for (int i = 0; i < 16; i++) {
    int idx = threadIdx.x + i * 256;
    int dr = idx >> 6, ec = idx & 63;
    Wt[(size_t)(mat * 1024 + h * 64 + dr) * 1024 + e0 + ec] = (bf16_t)tile[ec][dr];
  }
}

// ---------------- GEMM: C[M][N] = A[M][K] * Bt[N][K]^T ----------------
// MODE 0: bf16 out.  MODE 1: f32 out + bias.
// 128x128 tile, BK=32, 256 threads (4 waves, 2x2 wave grid, each wave 4x4 of 16x16).

template <int MODE>
__global__ __launch_bounds__(256) void gemm_bt(const bf16_t* __restrict__ A,
                                               const bf16_t* __restrict__ Bt,
                                               void* __restrict__ Cout,
                                               const float* __restrict__ bias,
                                               int M, int N, int K) {
  __shared__ bf16_t lA[128 * 32];
  __shared__ bf16_t lB[128 * 32];
  const int tid = threadIdx.x;
  const int l = tid & 63, w = tid >> 6;
  const int g = l >> 4, lg = l & 15;
  const int wr = w >> 1, wc = w & 1;
  const long brow = (long)blockIdx.y * 128;
  const long bcol = (long)blockIdx.x * 128;

  f32x4 acc[4][4];
  #pragma unroll
  for (int m = 0; m < 4; m++)
    #pragma unroll
    for (int n = 0; n < 4; n++) acc[m][n] = (f32x4){0.f, 0.f, 0.f, 0.f};

  const bf16_t* Ab = A + brow * K;
  const bf16_t* Bb = Bt + bcol * K;
  const int c0 = tid, c1 = tid + 256;
  const int r0 = c0 >> 2, o0 = (c0 & 3) * 8;
  const int r1 = c1 >> 2, o1 = (c1 & 3) * 8;

  for (int k0 = 0; k0 < K; k0 += 32) {
    __syncthreads();
    gload_lds16(Ab + (long)r0 * K + k0 + o0, lA + c0 * 8);
    gload_lds16(Ab + (long)r1 * K + k0 + o1, lA + c1 * 8);
    gload_lds16(Bb + (long)r0 * K + k0 + o0, lB + c0 * 8);
    gload_lds16(Bb + (long)r1 * K + k0 + o1, lB + c1 * 8);
    __syncthreads();
    bf16x8 af[4], bfr[4];
    #pragma unroll
    for (int m = 0; m < 4; m++)
      af[m] = *(const bf16x8*)(lA + (wr * 64 + m * 16 + lg) * 32 + g * 8);
    #pragma unroll
    for (int n = 0; n < 4; n++)
      bfr[n] = *(const bf16x8*)(lB + (wc * 64 + n * 16 + lg) * 32 + g * 8);
    #pragma unroll
    for (int m = 0; m < 4; m++)
      #pragma unroll
      for (int n = 0; n < 4; n++)
        acc[m][n] = __builtin_amdgcn_mfma_f32_16x16x32_bf16(af[m], bfr[n], acc[m][n], 0, 0, 0);
  }

  #pragma unroll
  for (int m = 0; m < 4; m++) {
    #pragma unroll
    for (int n = 0; n < 4; n++) {
      long row0 = brow + wr * 64 + m * 16 + g * 4;
      long col  = bcol + wc * 64 + n * 16 + lg;
      if (MODE == 0) {
        bf16_t* C = (bf16_t*)Cout;
        #pragma unroll
        for (int r = 0; r < 4; r++) C[(row0 + r) * N + col] = (bf16_t)acc[m][n][r];
      } else {
        float* C = (float*)Cout;
        float bv = bias[col];
        #pragma unroll
        for (int r = 0; r < 4; r++) C[(row0 + r) * N + col] = acc[m][n][r] + bv;
      }
    }
  }
}

// ---------------- flash attention ----------------
// grid (S/64, B*H), 256 threads. Wave w owns q-rows [qb+16w, qb+16w+16).
// KV tile = 64. Q/K frags direct from global; V staged blocked in LDS + tr-reads;
// P via per-wave XOR-swizzled LDS round-trip.

__global__ __launch_bounds__(256) void mha_attn(const bf16_t* __restrict__ QKV,
                                                bf16_t* __restrict__ AO) {
  __shared__ bf16_t Vlds[64 * 64];       // [4 jblk][4 dblk][16][16]
  __shared__ bf16_t Plds[4][16 * 64];    // per-wave P, swizzled
  const int tid = threadIdx.x;
  const int l = tid & 63, w = tid >> 6;
  const int g = l >> 4, lg = l & 15;
  const int b = blockIdx.y >> 4, h = blockIdx.y & 15;
  const int qb = blockIdx.x * 64;

  const bf16_t* Qb = QKV + (size_t)b * A_S * A_LD + h * 64;
  const bf16_t* Kb = Qb + 1024;
  const bf16_t* Vb = Qb + 2048;

  bf16x8 qf[2];
  {
    const bf16_t* qrow = Qb + (size_t)(qb + w * 16 + lg) * A_LD;
    qf[0] = *(const bf16x8*)(qrow + g * 8);
    qf[1] = *(const bf16x8*)(qrow + 32 + g * 8);
  }

  f32x4 o[4];
  #pragma unroll
  for (int d = 0; d < 4; d++) o[d] = (f32x4){0.f, 0.f, 0.f, 0.f};
  float mrow[4] = {-1e30f, -1e30f, -1e30f, -1e30f};
  float lrow[4] = {0.f, 0.f, 0.f, 0.f};

  bf16_t* Pw = &Plds[w][0];
  uint32_t vbase = (uint32_t)(uintptr_t)(__attribute__((address_space(3))) bf16_t*)&Vlds[0];

  const int tmax = qb / 64 + 1;
  for (int t = 0; t < tmax; t++) {
    __syncthreads();
    // stage V tile into blocked layout (linear LDS dest, per-lane gather src)
    #pragma unroll
    for (int i = 0; i < 2; i++) {
      int c = tid + i * 256;
      int blk = c >> 5, jr = (c >> 1) & 15, hf = c & 1;
      int j = (blk >> 2) * 16 + jr, d = (blk & 3) * 16 + hf * 8;
      gload_lds16(Vb + (size_t)(t * 64 + j) * A_LD + d, Vlds + c * 8);
    }
    // QK^T
    f32x4 sc[4];
    #pragma unroll
    for (int nt = 0; nt < 4; nt++) {
      const bf16_t* krow = Kb + (size_t)(t * 64 + nt * 16 + lg) * A_LD;
      bf16x8 kf0 = *(const bf16x8*)(krow + g * 8);
      bf16x8 kf1 = *(const bf16x8*)(krow + 32 + g * 8);
      f32x4 s = (f32x4){0.f, 0.f, 0.f, 0.f};
      s = __builtin_amdgcn_mfma_f32_16x16x32_bf16(qf[0], kf0, s, 0, 0, 0);
      s = __builtin_amdgcn_mfma_f32_16x16x32_bf16(qf[1], kf1, s, 0, 0, 0);
      sc[nt] = s;
    }
    // scale + causal mask (only the diagonal tile needs it)
    const bool lastt = (t == tmax - 1);
    #pragma unroll
    for (int nt = 0; nt < 4; nt++)
      #pragma unroll
      for (int r = 0; r < 4; r++) {
        float v = sc[nt][r] * 0.125f;
        if (lastt) {
          int qi = qb + w * 16 + g * 4 + r;
          int kj = t * 64 + nt * 16 + lg;
          if (kj > qi) v = -1e30f;
        }
        sc[nt][r] = v;
      }
    // online softmax (row i = 4g+r lives across lanes g*16..g*16+15)
    float alpha[4];
    float pvv[4][4];
    #pragma unroll
    for (int r = 0; r < 4; r++) {
      float mt = fmaxf(fmaxf(sc[0][r], sc[1][r]), fmaxf(sc[2][r], sc[3][r]));
      mt = fmaxf(mt, __shfl_xor(mt, 1));
      mt = fmaxf(mt, __shfl_xor(mt, 2));
      mt = fmaxf(mt, __shfl_xor(mt, 4));
      mt = fmaxf(mt, __shfl_xor(mt, 8));
      float mn = fmaxf(mrow[r], mt);
      alpha[r] = __expf(mrow[r] - mn);
      mrow[r] = mn;
      float rs = 0.f;
      #pragma unroll
      for (int nt = 0; nt < 4; nt++) {
        float p = __expf(sc[nt][r] - mn);
        pvv[nt][r] = p;
        rs += p;
      }
      rs += __shfl_xor(rs, 1);
      rs += __shfl_xor(rs, 2);
      rs += __shfl_xor(rs, 4);
      rs += __shfl_xor(rs, 8);
      lrow[r] = lrow[r] * alpha[r] + rs;
    }
    #pragma unroll
    for (int db = 0; db < 4; db++)
      #pragma unroll
      for (int r = 0; r < 4; r++) o[db][r] *= alpha[r];
    // write P (bf16) to swizzled per-wave LDS: P[i=4g+r][j=nt*16+lg]
    #pragma unroll
    for (int nt = 0; nt < 4; nt++)
      #pragma unroll
      for (int r = 0; r < 4; r++) {
        int i = g * 4 + r;
        int byteoff = ((nt * 16 + lg) * 2) ^ ((i & 7) << 4);
        *(bf16_t*)((char*)Pw + i * 128 + byteoff) = (bf16_t)pvv[nt][r];
      }
    __syncthreads();  // V staged (drains vmcnt)
    // V fragments via hardware transpose reads
    V8 vf[4][2];
    #pragma unroll
    for (int db = 0; db < 4; db++)
      #pragma unroll
      for (int kk = 0; kk < 2; kk++) {
        int jb0 = kk * 2 + (g >> 1);
        uint32_t base = vbase + (uint32_t)((jb0 * 4 + db) * 512 + (g & 1) * 256 + lg * 8);
        bf16x4 t0, t1;
        asm volatile("ds_read_b64_tr_b16 %0, %1" : "=v"(t0) : "v"(base));
        asm volatile("ds_read_b64_tr_b16 %0, %1 offset:128" : "=v"(t1) : "v"(base));
        vf[db][kk].h[0] = t0;
        vf[db][kk].h[1] = t1;
      }
    // P fragments (contiguous 16B, de-swizzled)
    bf16x8 pf[2];
    #pragma unroll
    for (int kk = 0; kk < 2; kk++) {
      int colb = (kk * 64 + g * 16) ^ ((lg & 7) << 4);
      pf[kk] = *(const bf16x8*)((const char*)Pw + lg * 128 + colb);
    }
    asm volatile("s_waitcnt lgkmcnt(0)" ::: "memory");
    __builtin_amdgcn_sched_barrier(0);  // rule #18: keep MFMAs below the wait
    #pragma unroll
    for (int db = 0; db < 4; db++) {
      o[db] = __builtin_amdgcn_mfma_f32_16x16x32_bf16(pf[0], vf[db][0].v8, o[db], 0, 0, 0);
      o[db] = __builtin_amdgcn_mfma_f32_16x16x32_bf16(pf[1], vf[db][1].v8, o[db], 0, 0, 0);
    }
  }
  // epilogue: AO[b*S+s][h*64+d] = o / l
  #pragma unroll
  for (int db = 0; db < 4; db++)
    #pragma unroll
    for (int r = 0; r < 4; r++) {
      size_t row = (size_t)b * A_S + qb + w * 16 + g * 4 + r;
      int col = h * 64 + db * 16 + lg;
      AO[row * 1024 + col] = (bf16_t)(o[db][r] / lrow[r]);
    }
}

// ---------------- launch ----------------

extern "C" void kernel_launch(void* const* d_in, const int* in_sizes, int n_in,
                              void* d_out, int out_size, void* d_ws, size_t ws_size,
                              hipStream_t stream) {
  (void)in_sizes; (void)n_in; (void)out_size; (void)ws_size;
  const float* X  = (const float*)d_in[0];
  const float* Wq = (const float*)d_in[1];
  const float* Wk = (const float*)d_in[2];
  const float* Wv = (const float*)d_in[3];
  const float* Wo = (const float*)d_in[4];
  const float* bo = (const float*)d_in[5];
  float* out = (float*)d_out;

  char* ws = (char*)d_ws;
  bf16_t* Xb  = (bf16_t*)ws;                          // 16 MiB  [8192][1024]
  bf16_t* AO  = Xb;                                   // reuse (Xb dead after QKV GEMM)
  bf16_t* Wt  = (bf16_t*)(ws + (16u << 20));          // 6 MiB   [3072][1024]
  bf16_t* Wob = (bf16_t*)(ws + (22u << 20));          // 2 MiB   [1024][1024]
  bf16_t* QKV = (bf16_t*)(ws + (24u << 20));          // 48 MiB  [8192][3072]

  // 1. X -> bf16 (8192*1024 elems, 8/thread)
  mha_cvt_bf16<<<dim3(4096), dim3(256), 0, stream>>>(X, Xb);
  // 2. weights
  mha_prep_w<<<dim3(16, 48), dim3(256), 0, stream>>>(Wq, Wk, Wv, Wt);
  mha_cvt_bf16<<<dim3(512), dim3(256), 0, stream>>>(Wo, Wob);
  // 3. QKV = Xb @ Wt^T   [8192 x 3072], K=1024
  gemm_bt<0><<<dim3(3072 / 128, 8192 / 128), dim3(256), 0, stream>>>(
      Xb, Wt, (void*)QKV, nullptr, 8192, 3072, 1024);
  // 4. attention
  mha_attn<<<dim3(A_S / 64, 64), dim3(256), 0, stream>>>(QKV, AO);
  // 5. out = AO @ Wob^T + bo   [8192 x 1024] f32
  gemm_bt<1><<<dim3(1024 / 128, 8192 / 128), dim3(256), 0, stream>>>(
      AO, Wob, (void*)out, bo, 8192, 1024, 1024);
}

// Round 2
// 238.511 us; speedup vs baseline: 1.8365x; 1.8365x over previous
//
#include <hip/hip_runtime.h>
#include <stdint.h>

// MHA forward: B=4, S=2048, E=1024, H=16, Dh=64, causal, fp32 I/O, bf16 MFMA compute.
//
// Pipeline:
//   1. cvt X -> Xb (bf16 [8192][1024])
//   2. prep_w: Wq/Wk/Wv [16][1024][64] -> Wt bf16 [3072][1024] (B^T layout)
//   3. cvt Wo -> Wob bf16 [1024][1024]
//   4. gemm_bt<0>: QKV[8192][3072] bf16 = Xb @ Wt^T
//   5. mha_attn2: flash attention (32x32 MFMA, swapped-QK, in-register softmax) -> AO bf16
//   6. gemm_bt<1>: out f32 = AO @ Wob^T + bo

typedef __bf16 bf16_t;
typedef __bf16 bf16x4 __attribute__((ext_vector_type(4)));
typedef __bf16 bf16x8 __attribute__((ext_vector_type(8)));
typedef float  f32x4  __attribute__((ext_vector_type(4)));
typedef float  f32x16 __attribute__((ext_vector_type(16)));
typedef unsigned int u32;

union V8 { bf16x8 v8; bf16x4 h[2]; u32 w[4]; };

__device__ __forceinline__ void gload_lds16(const void* g, void* l) {
  __builtin_amdgcn_global_load_lds((const __attribute__((address_space(1))) void*)g,
                                   (__attribute__((address_space(3))) void*)l, 16, 0, 0);
}

// ---------------- conversion kernels ----------------

__global__ void mha_cvt_bf16(const float* __restrict__ in, bf16_t* __restrict__ out) {
  size_t i = ((size_t)blockIdx.x * 256 + threadIdx.x) * 8;
  const float4* p = (const float4*)(in + i);
  float4 a = p[0], b = p[1];
  bf16x8 o;
  o[0] = (__bf16)a.x; o[1] = (__bf16)a.y; o[2] = (__bf16)a.z; o[3] = (__bf16)a.w;
  o[4] = (__bf16)b.x; o[5] = (__bf16)b.y; o[6] = (__bf16)b.z; o[7] = (__bf16)b.w;
  *(bf16x8*)(out + i) = o;
}

// Wq/Wk/Wv [H=16][E=1024][Dh=64] fp32 -> Wt [3072][1024] bf16
__global__ void mha_prep_w(const float* __restrict__ Wq, const float* __restrict__ Wk,
                           const float* __restrict__ Wv, bf16_t* __restrict__ Wt) {
  __shared__ float tile[64][65];
  const int e0 = blockIdx.x * 64;
  const int mh = blockIdx.y;
  const int mat = mh >> 4, h = mh & 15;
  const float* W = (mat == 0) ? Wq : (mat == 1) ? Wk : Wv;
  #pragma unroll
  for (int i = 0; i < 16; i++) {
    int idx = threadIdx.x + i * 256;
    int er = idx >> 6, d = idx & 63;
    tile[er][d] = W[(size_t)(h * 1024 + e0 + er) * 64 + d];
  }
  __syncthreads();
  #pragma unroll
  for (int i = 0; i < 16; i++) {
    int idx = threadIdx.x + i * 256;
    int dr = idx >> 6, ec = idx & 63;
    Wt[(size_t)(mat * 1024 + h * 64 + dr) * 1024 + e0 + ec] = (bf16_t)tile[ec][dr];
  }
}

// ---------------- GEMM: C[M][N] = A[M][K] * Bt[N][K]^T ----------------

template <int MODE>
__global__ __launch_bounds__(256) void gemm_bt(const bf16_t* __restrict__ A,
                                               const bf16_t* __restrict__ Bt,
                                               void* __restrict__ Cout,
                                               const float* __restrict__ bias,
                                               int M, int N, int K) {
  __shared__ bf16_t lA[128 * 32];
  __shared__ bf16_t lB[128 * 32];
  const int tid = threadIdx.x;
  const int l = tid & 63, w = tid >> 6;
  const int g = l >> 4, lg = l & 15;
  const int wr = w >> 1, wc = w & 1;
  const long brow = (long)blockIdx.y * 128;
  const long bcol = (long)blockIdx.x * 128;

  f32x4 acc[4][4];
  #pragma unroll
  for (int m = 0; m < 4; m++)
    #pragma unroll
    for (int n = 0; n < 4; n++) acc[m][n] = (f32x4){0.f, 0.f, 0.f, 0.f};

  const bf16_t* Ab = A + brow * K;
  const bf16_t* Bb = Bt + bcol * K;
  const int c0 = tid, c1 = tid + 256;
  const int r0 = c0 >> 2, o0 = (c0 & 3) * 8;
  const int r1 = c1 >> 2, o1 = (c1 & 3) * 8;

  for (int k0 = 0; k0 < K; k0 += 32) {
    __syncthreads();
    gload_lds16(Ab + (long)r0 * K + k0 + o0, lA + c0 * 8);
    gload_lds16(Ab + (long)r1 * K + k0 + o1, lA + c1 * 8);
    gload_lds16(Bb + (long)r0 * K + k0 + o0, lB + c0 * 8);
    gload_lds16(Bb + (long)r1 * K + k0 + o1, lB + c1 * 8);
    __syncthreads();
    bf16x8 af[4], bfr[4];
    #pragma unroll
    for (int m = 0; m < 4; m++)
      af[m] = *(const bf16x8*)(lA + (wr * 64 + m * 16 + lg) * 32 + g * 8);
    #pragma unroll
    for (int n = 0; n < 4; n++)
      bfr[n] = *(const bf16x8*)(lB + (wc * 64 + n * 16 + lg) * 32 + g * 8);
    #pragma unroll
    for (int m = 0; m < 4; m++)
      #pragma unroll
      for (int n = 0; n < 4; n++)
        acc[m][n] = __builtin_amdgcn_mfma_f32_16x16x32_bf16(af[m], bfr[n], acc[m][n], 0, 0, 0);
  }

  #pragma unroll
  for (int m = 0; m < 4; m++) {
    #pragma unroll
    for (int n = 0; n < 4; n++) {
      long row0 = brow + wr * 64 + m * 16 + g * 4;
      long col  = bcol + wc * 64 + n * 16 + lg;
      if (MODE == 0) {
        bf16_t* C = (bf16_t*)Cout;
        #pragma unroll
        for (int r = 0; r < 4; r++) C[(row0 + r) * N + col] = (bf16_t)acc[m][n][r];
      } else {
        float* C = (float*)Cout;
        float bv = bias[col];
        #pragma unroll
        for (int r = 0; r < 4; r++) C[(row0 + r) * N + col] = acc[m][n][r] + bv;
      }
    }
  }
}

// ---------------- flash attention, 32x32 MFMA, swapped-QK ----------------
// 256 thr = 4 waves; wave w owns 32 q-rows (qw = stripe*128 + w*32). KV tile 64.
// S^T = K.Q^T via mfma(A=K,B=Q^T): lane holds P-row for q = lane&31 (32 f32).
// O^T = V^T.P^T via mfma(A=V^T (tr-reads), B=P^T (cvt_pk+permlane32_swap)).
// Per-lane online softmax: serial fmax/fadd over 32 regs + one shfl_xor(32).

__global__ __launch_bounds__(256) void mha_attn2(const bf16_t* __restrict__ QKV,
                                                 bf16_t* __restrict__ AO) {
  __shared__ __align__(16) char smem[16384];  // V tile: 8 KB; epilogue O: 16 KB
  const int tid = threadIdx.x;
  const int l = tid & 63, w = tid >> 6;
  const int q31 = l & 31;
  const int hi = l >> 5;           // k-slice half
  const int hb = (l >> 4) & 1;     // d-subtile select bit
  const int lg = l & 15;

  // XCD-clustered, heavy-stripe-first decode: bid = xcd + 8*(bh_local + 8*sidx)
  const int bid = blockIdx.x;
  const int xcd = bid & 7, ii = bid >> 3;
  const int bh = xcd * 8 + (ii & 7);
  const int stripe = 15 - (ii >> 3);          // heavy (stripe 15) first
  const int b = bh >> 4, h = bh & 15;

  const int qw = stripe * 128 + w * 32;
  const bf16_t* Qp = QKV + (size_t)b * 2048 * 3072 + h * 64;
  const bf16_t* Kp = Qp + 1024;
  const bf16_t* Vp = Qp + 2048;

  // Q fragments (B-operand): lane holds Q[q31][16*ks + 8*hi + e]
  bf16x8 qf[4];
  {
    const bf16_t* qrow = Qp + (size_t)(qw + q31) * 3072 + hi * 8;
    #pragma unroll
    for (int ks = 0; ks < 4; ks++) qf[ks] = *(const bf16x8*)(qrow + ks * 16);
  }

  f32x16 o0, o1;                    // O^T accum: col q31, rows d (+0 / +32)
  #pragma unroll
  for (int r = 0; r < 16; r++) { o0[r] = 0.f; o1[r] = 0.f; }
  float m = -1e30f, lsum = 0.f;
  const float C = 0.18033688011112042f;   // (1/sqrt(64)) * log2(e)

  const int tmaxw = 2 * stripe + 1 + (w >> 1);
  const int T = 2 * stripe + 2;
  u32 vbase = (u32)(uintptr_t)(__attribute__((address_space(3))) char*)smem;

  for (int t = 0; t < T; t++) {
    u32 paw[4][4];
    __syncthreads();
    // stage V tile (64x64) into [jsub 4][dsub 4][16][16] subtiles (linear LDS dest)
    #pragma unroll
    for (int it = 0; it < 2; it++) {
      int cc = tid + it * 256;
      int st = cc >> 5, qq = cc & 31;
      int j = (st >> 2) * 16 + (qq >> 1), d = (st & 3) * 16 + (qq & 1) * 8;
      gload_lds16(Vp + (size_t)(t * 64 + j) * 3072 + d, (bf16_t*)smem + cc * 8);
    }
    if (t < tmaxw) {
      // ---- QK^T (swapped): p0/p1 = S^T for kv blocks [t64, t64+32), [t64+32, +64)
      f32x16 p0, p1;
      #pragma unroll
      for (int r = 0; r < 16; r++) { p0[r] = 0.f; p1[r] = 0.f; }
      {
        const bf16_t* k0 = Kp + (size_t)(t * 64 + q31) * 3072 + hi * 8;
        const bf16_t* k1 = k0 + (size_t)32 * 3072;
        bf16x8 kf0[4], kf1[4];
        #pragma unroll
        for (int ks = 0; ks < 4; ks++) {
          kf0[ks] = *(const bf16x8*)(k0 + ks * 16);
          kf1[ks] = *(const bf16x8*)(k1 + ks * 16);
        }
        #pragma unroll
        for (int ks = 0; ks < 4; ks++) {
          p0 = __builtin_amdgcn_mfma_f32_32x32x16_bf16(kf0[ks], qf[ks], p0, 0, 0, 0);
          p1 = __builtin_amdgcn_mfma_f32_32x32x16_bf16(kf1[ks], qf[ks], p1, 0, 0, 0);
        }
      }
      // ---- causal mask (last needed tile only; reg r -> kv row)
      if (t == tmaxw - 1) {
        int q = qw + q31;
        int kvb = t * 64 + 4 * hi;
        #pragma unroll
        for (int r = 0; r < 16; r++) {
          int kv0 = kvb + (r & 3) + 8 * (r >> 2);
          if (kv0 > q) p0[r] = -1e30f;
          if (kv0 + 32 > q) p1[r] = -1e30f;
        }
      }
      // ---- online softmax, per-lane (lane owns row q31)
      float pm = p0[0];
      #pragma unroll
      for (int r = 1; r < 16; r++) pm = fmaxf(pm, p0[r]);
      #pragma unroll
      for (int r = 0; r < 16; r++) pm = fmaxf(pm, p1[r]);
      pm = fmaxf(pm, __shfl_xor(pm, 32));
      if (!__all(pm - m <= 64.f)) {     // defer-max THR = 8 natural units
        float mn = fmaxf(m, pm);
        float alpha = exp2f((m - mn) * C);
        #pragma unroll
        for (int r = 0; r < 16; r++) { o0[r] *= alpha; o1[r] *= alpha; }
        lsum *= alpha;
        m = mn;
      }
      float mc = m * C;
      float rs = 0.f;
      float pe[32];
      #pragma unroll
      for (int r = 0; r < 16; r++) { pe[r] = exp2f(fmaf(p0[r], C, -mc)); rs += pe[r]; }
      #pragma unroll
      for (int r = 0; r < 16; r++) { pe[16 + r] = exp2f(fmaf(p1[r], C, -mc)); rs += pe[16 + r]; }
      rs += __shfl_xor(rs, 32);
      lsum += rs;
      // ---- pack P^T fragments: pa[ks] holds P[q31][16ks+8hi+e] as bf16x8
      #pragma unroll
      for (int gblk = 0; gblk < 4; gblk++) {   // gblk = ks
        int base = gblk * 8;                    // pe[base..base+7]
        u32 u0, u1, v0, v1;
        asm("v_cvt_pk_bf16_f32 %0, %1, %2" : "=v"(u0) : "v"(pe[base + 0]), "v"(pe[base + 1]));
        asm("v_cvt_pk_bf16_f32 %0, %1, %2" : "=v"(u1) : "v"(pe[base + 2]), "v"(pe[base + 3]));
        asm("v_cvt_pk_bf16_f32 %0, %1, %2" : "=v"(v0) : "v"(pe[base + 4]), "v"(pe[base + 5]));
        asm("v_cvt_pk_bf16_f32 %0, %1, %2" : "=v"(v1) : "v"(pe[base + 6]), "v"(pe[base + 7]));
        asm("v_permlane32_swap_b32 %0, %1" : "+v"(u0), "+v"(v0));
        asm("v_permlane32_swap_b32 %0, %1" : "+v"(u1), "+v"(v1));
        paw[gblk][0] = u0; paw[gblk][1] = u1; paw[gblk][2] = v0; paw[gblk][3] = v1;
      }
    }
    __syncthreads();   // V staged (drains vmcnt); all warps participate
    if (t < tmaxw) {
      // ---- V^T fragments via hardware transpose reads
      V8 vf[2][4];
      #pragma unroll
      for (int mb = 0; mb < 2; mb++)
        #pragma unroll
        for (int ks = 0; ks < 4; ks++) {
          u32 base = vbase + (u32)(((ks * 4 + 2 * mb + hb) << 9) + hi * 256 + lg * 8);
          bf16x4 t0, t1;
          asm volatile("ds_read_b64_tr_b16 %0, %1" : "=v"(t0) : "v"(base));
          asm volatile("ds_read_b64_tr_b16 %0, %1 offset:128" : "=v"(t1) : "v"(base));
          vf[mb][ks].h[0] = t0; vf[mb][ks].h[1] = t1;
        }
      asm volatile("s_waitcnt lgkmcnt(0)" ::: "memory");
      __builtin_amdgcn_sched_barrier(0);   // rule #18: keep MFMAs below the wait
      #pragma unroll
      for (int ks = 0; ks < 4; ks++) {
        V8 pa; pa.w[0] = paw[ks][0]; pa.w[1] = paw[ks][1]; pa.w[2] = paw[ks][2]; pa.w[3] = paw[ks][3];
        o0 = __builtin_amdgcn_mfma_f32_32x32x16_bf16(vf[0][ks].v8, pa.v8, o0, 0, 0, 0);
        o1 = __builtin_amdgcn_mfma_f32_32x32x16_bf16(vf[1][ks].v8, pa.v8, o1, 0, 0, 0);
      }
    }
  }

  // ---- epilogue: normalize, transpose via swizzled LDS, coalesced store
  float linv = 1.f / lsum;
  __syncthreads();
  bf16_t* ow = (bf16_t*)smem + w * 2048;   // 4 KB per warp: [32 q][64 d] swizzled
  #pragma unroll
  for (int mb = 0; mb < 2; mb++)
    #pragma unroll
    for (int r = 0; r < 16; r += 2) {
      int d = mb * 32 + (r & 3) + 8 * (r >> 2) + 4 * hi;
      float a0 = (mb ? o1[r] : o0[r]) * linv;
      float a1 = (mb ? o1[r + 1] : o0[r + 1]) * linv;
      u32 pk;
      asm("v_cvt_pk_bf16_f32 %0, %1, %2" : "=v"(pk) : "v"(a0), "v"(a1));
      int byteoff = q31 * 128 + ((d * 2) ^ ((q31 & 7) << 4));
      *(u32*)((char*)ow + byteoff) = pk;
    }
  __syncthreads();
  const size_t aorow0 = (size_t)b * 2048 + qw;
  #pragma unroll
  for (int it = 0; it < 4; it++) {
    int idx = it * 64 + l;
    int q = idx >> 3, c = idx & 7;
    bf16x8 v8 = *(const bf16x8*)((const char*)ow + q * 128 + ((c * 16) ^ ((q & 7) << 4)));
    *(bf16x8*)(AO + (aorow0 + q) * 1024 + h * 64 + c * 8) = v8;
  }
}

// ---------------- launch ----------------

extern "C" void kernel_launch(void* const* d_in, const int* in_sizes, int n_in,
                              void* d_out, int out_size, void* d_ws, size_t ws_size,
                              hipStream_t stream) {
  (void)in_sizes; (void)n_in; (void)out_size; (void)ws_size;
  const float* X  = (const float*)d_in[0];
  const float* Wq = (const float*)d_in[1];
  const float* Wk = (const float*)d_in[2];
  const float* Wv = (const float*)d_in[3];
  const float* Wo = (const float*)d_in[4];
  const float* bo = (const float*)d_in[5];
  float* out = (float*)d_out;

  char* ws = (char*)d_ws;
  bf16_t* Xb  = (bf16_t*)ws;                          // 16 MiB  [8192][1024]
  bf16_t* AO  = Xb;                                   // reuse (Xb dead after QKV GEMM)
  bf16_t* Wt  = (bf16_t*)(ws + (16u << 20));          // 6 MiB   [3072][1024]
  bf16_t* Wob = (bf16_t*)(ws + (22u << 20));          // 2 MiB   [1024][1024]
  bf16_t* QKV = (bf16_t*)(ws + (24u << 20));          // 48 MiB  [8192][3072]

  mha_cvt_bf16<<<dim3(4096), dim3(256), 0, stream>>>(X, Xb);
  mha_prep_w<<<dim3(16, 48), dim3(256), 0, stream>>>(Wq, Wk, Wv, Wt);
  mha_cvt_bf16<<<dim3(512), dim3(256), 0, stream>>>(Wo, Wob);
  gemm_bt<0><<<dim3(3072 / 128, 8192 / 128), dim3(256), 0, stream>>>(
      Xb, Wt, (void*)QKV, nullptr, 8192, 3072, 1024);
  mha_attn2<<<dim3(1024), dim3(256), 0, stream>>>(QKV, AO);
  gemm_bt<1><<<dim3(1024 / 128, 8192 / 128), dim3(256), 0, stream>>>(
      AO, Wob, (void*)out, bo, 8192, 1024, 1024);
}

// Round 3
// 188.477 us; speedup vs baseline: 2.3240x; 1.2655x over previous
//
#include <hip/hip_runtime.h>
#include <stdint.h>

// MHA forward: B=4, S=2048, E=1024, H=16, Dh=64, causal, fp32 I/O, bf16 MFMA compute.
//
// Pipeline:
//   1. cvt X -> Xb (bf16 [8192][1024])
//   2. prep_w: Wq/Wk/Wv [16][1024][64] -> Wt bf16 [3072][1024] (B^T layout)
//   3. cvt Wo -> Wob bf16 [1024][1024]
//   4. gemm_bt<0>: QKV[8192][3072] bf16 = Xb @ Wt^T
//   5. mha_attn3: flash attention, K+V in double-buffered LDS, counted-vmcnt pipeline
//   6. gemm_bt<1>: out f32 = AO @ Wob^T + bo

typedef __bf16 bf16_t;
typedef __bf16 bf16x4 __attribute__((ext_vector_type(4)));
typedef __bf16 bf16x8 __attribute__((ext_vector_type(8)));
typedef float  f32x4  __attribute__((ext_vector_type(4)));
typedef float  f32x16 __attribute__((ext_vector_type(16)));
typedef unsigned int u32;

union V8 { bf16x8 v8; bf16x4 h[2]; u32 w[4]; };

__device__ __forceinline__ void gload_lds16(const void* g, void* l) {
  __builtin_amdgcn_global_load_lds((const __attribute__((address_space(1))) void*)g,
                                   (__attribute__((address_space(3))) void*)l, 16, 0, 0);
}

// ---------------- conversion kernels ----------------

__global__ void mha_cvt_bf16(const float* __restrict__ in, bf16_t* __restrict__ out) {
  size_t i = ((size_t)blockIdx.x * 256 + threadIdx.x) * 8;
  const float4* p = (const float4*)(in + i);
  float4 a = p[0], b = p[1];
  bf16x8 o;
  o[0] = (__bf16)a.x; o[1] = (__bf16)a.y; o[2] = (__bf16)a.z; o[3] = (__bf16)a.w;
  o[4] = (__bf16)b.x; o[5] = (__bf16)b.y; o[6] = (__bf16)b.z; o[7] = (__bf16)b.w;
  *(bf16x8*)(out + i) = o;
}

// Wq/Wk/Wv [H=16][E=1024][Dh=64] fp32 -> Wt [3072][1024] bf16
__global__ void mha_prep_w(const float* __restrict__ Wq, const float* __restrict__ Wk,
                           const float* __restrict__ Wv, bf16_t* __restrict__ Wt) {
  __shared__ float tile[64][65];
  const int e0 = blockIdx.x * 64;
  const int mh = blockIdx.y;
  const int mat = mh >> 4, h = mh & 15;
  const float* W = (mat == 0) ? Wq : (mat == 1) ? Wk : Wv;
  #pragma unroll
  for (int i = 0; i < 16; i++) {
    int idx = threadIdx.x + i * 256;
    int er = idx >> 6, d = idx & 63;
    tile[er][d] = W[(size_t)(h * 1024 + e0 + er) * 64 + d];
  }
  __syncthreads();
  #pragma unroll
  for (int i = 0; i < 16; i++) {
    int idx = threadIdx.x + i * 256;
    int dr = idx >> 6, ec = idx & 63;
    Wt[(size_t)(mat * 1024 + h * 64 + dr) * 1024 + e0 + ec] = (bf16_t)tile[ec][dr];
  }
}

// ---------------- GEMM: C[M][N] = A[M][K] * Bt[N][K]^T ----------------

template <int MODE>
__global__ __launch_bounds__(256) void gemm_bt(const bf16_t* __restrict__ A,
                                               const bf16_t* __restrict__ Bt,
                                               void* __restrict__ Cout,
                                               const float* __restrict__ bias,
                                               int M, int N, int K) {
  __shared__ bf16_t lA[128 * 32];
  __shared__ bf16_t lB[128 * 32];
  const int tid = threadIdx.x;
  const int l = tid & 63, w = tid >> 6;
  const int g = l >> 4, lg = l & 15;
  const int wr = w >> 1, wc = w & 1;
  const long brow = (long)blockIdx.y * 128;
  const long bcol = (long)blockIdx.x * 128;

  f32x4 acc[4][4];
  #pragma unroll
  for (int m = 0; m < 4; m++)
    #pragma unroll
    for (int n = 0; n < 4; n++) acc[m][n] = (f32x4){0.f, 0.f, 0.f, 0.f};

  const bf16_t* Ab = A + brow * K;
  const bf16_t* Bb = Bt + bcol * K;
  const int c0 = tid, c1 = tid + 256;
  const int r0 = c0 >> 2, o0 = (c0 & 3) * 8;
  const int r1 = c1 >> 2, o1 = (c1 & 3) * 8;

  for (int k0 = 0; k0 < K; k0 += 32) {
    __syncthreads();
    gload_lds16(Ab + (long)r0 * K + k0 + o0, lA + c0 * 8);
    gload_lds16(Ab + (long)r1 * K + k0 + o1, lA + c1 * 8);
    gload_lds16(Bb + (long)r0 * K + k0 + o0, lB + c0 * 8);
    gload_lds16(Bb + (long)r1 * K + k0 + o1, lB + c1 * 8);
    __syncthreads();
    bf16x8 af[4], bfr[4];
    #pragma unroll
    for (int m = 0; m < 4; m++)
      af[m] = *(const bf16x8*)(lA + (wr * 64 + m * 16 + lg) * 32 + g * 8);
    #pragma unroll
    for (int n = 0; n < 4; n++)
      bfr[n] = *(const bf16x8*)(lB + (wc * 64 + n * 16 + lg) * 32 + g * 8);
    #pragma unroll
    for (int m = 0; m < 4; m++)
      #pragma unroll
      for (int n = 0; n < 4; n++)
        acc[m][n] = __builtin_amdgcn_mfma_f32_16x16x32_bf16(af[m], bfr[n], acc[m][n], 0, 0, 0);
  }

  #pragma unroll
  for (int m = 0; m < 4; m++) {
    #pragma unroll
    for (int n = 0; n < 4; n++) {
      long row0 = brow + wr * 64 + m * 16 + g * 4;
      long col  = bcol + wc * 64 + n * 16 + lg;
      if (MODE == 0) {
        bf16_t* C = (bf16_t*)Cout;
        #pragma unroll
        for (int r = 0; r < 4; r++) C[(row0 + r) * N + col] = (bf16_t)acc[m][n][r];
      } else {
        float* C = (float*)Cout;
        float bv = bias[col];
        #pragma unroll
        for (int r = 0; r < 4; r++) C[(row0 + r) * N + col] = acc[m][n][r] + bv;
      }
    }
  }
}

// ---------------- flash attention v3 ----------------
// 4 waves x 32 q-rows, KV tile 64. K+V double-buffered in LDS, staged via
// global_load_lds with counted s_waitcnt vmcnt(4) + raw s_barrier (T3/T4):
// stage(t+1) stays in flight across the whole tile-t compute.
// K LDS: row-major [64][64] bf16, XOR-swizzle byte^=((row&7)<<4), b128 reads.
// V LDS: [jsub4][dsub4][16][16] subtiles for ds_read_b64_tr_b16.
// Swapped QK^T (lane owns P-row), in-register softmax w/ tree reductions,
// cvt_pk+permlane32_swap P->bf16, O^T=V^T.P^T, defer-max THR=8.

__global__ __launch_bounds__(256, 4) void mha_attn3(const bf16_t* __restrict__ QKV,
                                                    bf16_t* __restrict__ AO) {
  __shared__ __align__(16) char smem[32768];  // K0 8K | K1 8K | V0 8K | V1 8K
  const int tid = threadIdx.x;
  const int l = tid & 63, w = tid >> 6;
  const int q31 = l & 31;
  const int hi = l >> 5;
  const int hb = (l >> 4) & 1;
  const int lg = l & 15;

  // XCD-clustered, heavy-stripe-first decode
  const int bid = blockIdx.x;
  const int xcd = bid & 7, ii = bid >> 3;
  const int bh = xcd * 8 + (ii & 7);
  const int stripe = 15 - (ii >> 3);
  const int b = bh >> 4, h = bh & 15;

  const int qw = stripe * 128 + w * 32;
  const bf16_t* Qp = QKV + (size_t)b * 2048 * 3072 + h * 64;
  const bf16_t* Kp = Qp + 1024;
  const bf16_t* Vp = Qp + 2048;

  bf16x8 qf[4];
  {
    const bf16_t* qrow = Qp + (size_t)(qw + q31) * 3072 + hi * 8;
    #pragma unroll
    for (int ks = 0; ks < 4; ks++) qf[ks] = *(const bf16x8*)(qrow + ks * 16);
  }

  f32x16 o0, o1;
  #pragma unroll
  for (int r = 0; r < 16; r++) { o0[r] = 0.f; o1[r] = 0.f; }
  float m = -1e30f, lsum = 0.f;
  const float Cf = 0.18033688011112042f;   // (1/sqrt(64)) * log2(e)

  const int tmaxw = 2 * stripe + 1 + (w >> 1);
  const int T = 2 * stripe + 2;
  const u32 ldsbase = (u32)(uintptr_t)(__attribute__((address_space(3))) char*)smem;

  // stage tile tt into buffer bi: 2 K-chunks + 2 V-chunks per wave (4 gload_lds)
  auto stage = [&](int tt, int bi) {
    char* kb = smem + bi * 8192;
    char* vb = smem + 16384 + bi * 8192;
    #pragma unroll
    for (int it = 0; it < 2; it++) {
      int c = tid + it * 256;
      // K: linear LDS [row][cb], source col pre-swizzled so swizzled read is correct
      int row = c >> 3, cb = (c & 7) * 16;
      int scb = cb ^ ((row & 7) << 4);
      gload_lds16(Kp + (size_t)(tt * 64 + row) * 3072 + (scb >> 1), kb + c * 16);
      // V: [jsub][dsub][16][16] blocked
      int st = c >> 5, qq = c & 31;
      int j = (st >> 2) * 16 + (qq >> 1), d = (st & 3) * 16 + (qq & 1) * 8;
      gload_lds16(Vp + (size_t)(tt * 64 + j) * 3072 + d, vb + c * 16);
    }
  };

  stage(0, 0);
  for (int t = 0; t < T; t++) {
    const int cur = t & 1;
    if (t + 1 < T) {
      stage(t + 1, cur ^ 1);
      __builtin_amdgcn_sched_barrier(0);
      asm volatile("s_waitcnt vmcnt(4)" ::: "memory");   // stage(t) done; stage(t+1) in flight
    } else {
      __builtin_amdgcn_sched_barrier(0);
      asm volatile("s_waitcnt vmcnt(0)" ::: "memory");   // final tile: full drain
    }
    __builtin_amdgcn_sched_barrier(0);
    __builtin_amdgcn_s_barrier();                        // b1: K(t),V(t) visible
    __builtin_amdgcn_sched_barrier(0);

    const bool active = (t < tmaxw);
    u32 paw[4][4];
    if (active) {
      // ---- QK^T from LDS (swizzled b128 reads)
      f32x16 p0, p1;
      #pragma unroll
      for (int r = 0; r < 16; r++) { p0[r] = 0.f; p1[r] = 0.f; }
      {
        const char* kb = smem + cur * 8192;
        const int rb0 = q31 * 128;
        const int swz = (l & 7) << 4;
        __builtin_amdgcn_s_setprio(1);
        #pragma unroll
        for (int ks = 0; ks < 4; ks++) {
          int colb = ((ks << 5) | (hi << 4)) ^ swz;
          bf16x8 kf0 = *(const bf16x8*)(kb + rb0 + colb);
          bf16x8 kf1 = *(const bf16x8*)(kb + 4096 + rb0 + colb);
          p0 = __builtin_amdgcn_mfma_f32_32x32x16_bf16(kf0, qf[ks], p0, 0, 0, 0);
          p1 = __builtin_amdgcn_mfma_f32_32x32x16_bf16(kf1, qf[ks], p1, 0, 0, 0);
        }
        __builtin_amdgcn_s_setprio(0);
      }
      // ---- causal mask (last needed tile only)
      if (t == tmaxw - 1) {
        int q = qw + q31;
        int kvb = t * 64 + 4 * hi;
        #pragma unroll
        for (int r = 0; r < 16; r++) {
          int kv0 = kvb + (r & 3) + 8 * (r >> 2);
          if (kv0 > q) p0[r] = -1e30f;
          if (kv0 + 32 > q) p1[r] = -1e30f;
        }
      }
      // ---- online softmax, tree reductions
      float t8[8];
      #pragma unroll
      for (int r = 0; r < 8; r++)
        t8[r] = fmaxf(fmaxf(p0[r], p0[r + 8]), fmaxf(p1[r], p1[r + 8]));
      float pm = fmaxf(fmaxf(fmaxf(t8[0], t8[4]), fmaxf(t8[1], t8[5])),
                       fmaxf(fmaxf(t8[2], t8[6]), fmaxf(t8[3], t8[7])));
      pm = fmaxf(pm, __shfl_xor(pm, 32));
      if (!__all(pm - m <= 64.f)) {      // defer-max THR = 8 natural units
        float mn = fmaxf(m, pm);
        float alpha = exp2f((m - mn) * Cf);
        #pragma unroll
        for (int r = 0; r < 16; r++) { o0[r] *= alpha; o1[r] *= alpha; }
        lsum *= alpha;
        m = mn;
      }
      float mc = m * Cf;
      #pragma unroll
      for (int r = 0; r < 16; r++) p0[r] = exp2f(fmaf(p0[r], Cf, -mc));
      #pragma unroll
      for (int r = 0; r < 16; r++) p1[r] = exp2f(fmaf(p1[r], Cf, -mc));
      float s8[8];
      #pragma unroll
      for (int r = 0; r < 8; r++)
        s8[r] = (p0[r] + p0[r + 8]) + (p1[r] + p1[r + 8]);
      float rs = ((s8[0] + s8[1]) + (s8[2] + s8[3])) + ((s8[4] + s8[5]) + (s8[6] + s8[7]));
      rs += __shfl_xor(rs, 32);
      lsum += rs;
      // ---- pack P^T fragments (cvt_pk + permlane32_swap)
      #pragma unroll
      for (int gblk = 0; gblk < 4; gblk++) {
        int base = (gblk & 1) * 8;
        float e0 = (gblk < 2) ? p0[base + 0] : p1[base + 0];
        float e1 = (gblk < 2) ? p0[base + 1] : p1[base + 1];
        float e2 = (gblk < 2) ? p0[base + 2] : p1[base + 2];
        float e3 = (gblk < 2) ? p0[base + 3] : p1[base + 3];
        float e4 = (gblk < 2) ? p0[base + 4] : p1[base + 4];
        float e5 = (gblk < 2) ? p0[base + 5] : p1[base + 5];
        float e6 = (gblk < 2) ? p0[base + 6] : p1[base + 6];
        float e7 = (gblk < 2) ? p0[base + 7] : p1[base + 7];
        u32 u0, u1, v0, v1;
        asm("v_cvt_pk_bf16_f32 %0, %1, %2" : "=v"(u0) : "v"(e0), "v"(e1));
        asm("v_cvt_pk_bf16_f32 %0, %1, %2" : "=v"(u1) : "v"(e2), "v"(e3));
        asm("v_cvt_pk_bf16_f32 %0, %1, %2" : "=v"(v0) : "v"(e4), "v"(e5));
        asm("v_cvt_pk_bf16_f32 %0, %1, %2" : "=v"(v1) : "v"(e6), "v"(e7));
        asm("v_permlane32_swap_b32 %0, %1" : "+v"(u0), "+v"(v0));
        asm("v_permlane32_swap_b32 %0, %1" : "+v"(u1), "+v"(v1));
        paw[gblk][0] = u0; paw[gblk][1] = u1; paw[gblk][2] = v0; paw[gblk][3] = v1;
      }
      // ---- V^T fragments via hardware transpose reads
      V8 vf[2][4];
      u32 vb = ldsbase + 16384u + (u32)cur * 8192u;
      #pragma unroll
      for (int mb = 0; mb < 2; mb++)
        #pragma unroll
        for (int ks = 0; ks < 4; ks++) {
          u32 base = vb + (u32)(((ks * 4 + 2 * mb + hb) << 9) + hi * 256 + lg * 8);
          bf16x4 t0, t1;
          asm volatile("ds_read_b64_tr_b16 %0, %1" : "=v"(t0) : "v"(base));
          asm volatile("ds_read_b64_tr_b16 %0, %1 offset:128" : "=v"(t1) : "v"(base));
          vf[mb][ks].h[0] = t0; vf[mb][ks].h[1] = t1;
        }
      asm volatile("s_waitcnt lgkmcnt(0)" ::: "memory");
      __builtin_amdgcn_sched_barrier(0);   // rule #18
      __builtin_amdgcn_s_setprio(1);
      #pragma unroll
      for (int ks = 0; ks < 4; ks++) {
        V8 pa; pa.w[0] = paw[ks][0]; pa.w[1] = paw[ks][1]; pa.w[2] = paw[ks][2]; pa.w[3] = paw[ks][3];
        o0 = __builtin_amdgcn_mfma_f32_32x32x16_bf16(vf[0][ks].v8, pa.v8, o0, 0, 0, 0);
        o1 = __builtin_amdgcn_mfma_f32_32x32x16_bf16(vf[1][ks].v8, pa.v8, o1, 0, 0, 0);
      }
      __builtin_amdgcn_s_setprio(0);
    }
    __builtin_amdgcn_sched_barrier(0);
    __builtin_amdgcn_s_barrier();                        // b2: buffers free for reuse
    __builtin_amdgcn_sched_barrier(0);
  }

  // ---- epilogue: normalize, transpose via swizzled LDS (first 16 KB), store
  float linv = 1.f / lsum;
  __syncthreads();
  bf16_t* ow = (bf16_t*)smem + w * 2048;
  #pragma unroll
  for (int mb = 0; mb < 2; mb++)
    #pragma unroll
    for (int r = 0; r < 16; r += 2) {
      int d = mb * 32 + (r & 3) + 8 * (r >> 2) + 4 * hi;
      float a0 = (mb ? o1[r] : o0[r]) * linv;
      float a1 = (mb ? o1[r + 1] : o0[r + 1]) * linv;
      u32 pk;
      asm("v_cvt_pk_bf16_f32 %0, %1, %2" : "=v"(pk) : "v"(a0), "v"(a1));
      int byteoff = q31 * 128 + ((d * 2) ^ ((q31 & 7) << 4));
      *(u32*)((char*)ow + byteoff) = pk;
    }
  __syncthreads();
  const size_t aorow0 = (size_t)b * 2048 + qw;
  #pragma unroll
  for (int it = 0; it < 4; it++) {
    int idx = it * 64 + l;
    int q = idx >> 3, c = idx & 7;
    bf16x8 v8 = *(const bf16x8*)((const char*)ow + q * 128 + ((c * 16) ^ ((q & 7) << 4)));
    *(bf16x8*)(AO + (aorow0 + q) * 1024 + h * 64 + c * 8) = v8;
  }
}

// ---------------- launch ----------------

extern "C" void kernel_launch(void* const* d_in, const int* in_sizes, int n_in,
                              void* d_out, int out_size, void* d_ws, size_t ws_size,
                              hipStream_t stream) {
  (void)in_sizes; (void)n_in; (void)out_size; (void)ws_size;
  const float* X  = (const float*)d_in[0];
  const float* Wq = (const float*)d_in[1];
  const float* Wk = (const float*)d_in[2];
  const float* Wv = (const float*)d_in[3];
  const float* Wo = (const float*)d_in[4];
  const float* bo = (const float*)d_in[5];
  float* out = (float*)d_out;

  char* ws = (char*)d_ws;
  bf16_t* Xb  = (bf16_t*)ws;                          // 16 MiB  [8192][1024]
  bf16_t* AO  = Xb;                                   // reuse (Xb dead after QKV GEMM)
  bf16_t* Wt  = (bf16_t*)(ws + (16u << 20));          // 6 MiB   [3072][1024]
  bf16_t* Wob = (bf16_t*)(ws + (22u << 20));          // 2 MiB   [1024][1024]
  bf16_t* QKV = (bf16_t*)(ws + (24u << 20));          // 48 MiB  [8192][3072]

  mha_cvt_bf16<<<dim3(4096), dim3(256), 0, stream>>>(X, Xb);
  mha_prep_w<<<dim3(16, 48), dim3(256), 0, stream>>>(Wq, Wk, Wv, Wt);
  mha_cvt_bf16<<<dim3(512), dim3(256), 0, stream>>>(Wo, Wob);
  gemm_bt<0><<<dim3(3072 / 128, 8192 / 128), dim3(256), 0, stream>>>(
      Xb, Wt, (void*)QKV, nullptr, 8192, 3072, 1024);
  mha_attn3<<<dim3(1024), dim3(256), 0, stream>>>(QKV, AO);
  gemm_bt<1><<<dim3(1024 / 128, 8192 / 128), dim3(256), 0, stream>>>(
      AO, Wob, (void*)out, bo, 8192, 1024, 1024);
}